// Round 9
// baseline (426.772 us; speedup 1.0000x reference)
//
#include <hip/hip_runtime.h>
#include <stdint.h>

// ---------------------------------------------------------------------------
// CrossAttentionRope: x(16,256,768), ctx(16,4096,768) f32 -> out(16,256,768) f32
// R9: R8 + ONE change — ctx f32->bf16 conversion folded into KV GEMM A-staging
//     (read f32, v_cvt_pk_bf16_f32 during LDS write; pattern verified in R7).
//     Standalone ctx cvt_kernel deleted. Everything else verbatim R8.
// ---------------------------------------------------------------------------

typedef __bf16 bf16x8 __attribute__((ext_vector_type(8)));
typedef unsigned short u16x8 __attribute__((ext_vector_type(8)));
typedef unsigned short u16x4 __attribute__((ext_vector_type(4)));
typedef uint32_t u32x4 __attribute__((ext_vector_type(4)));
typedef float f32x4 __attribute__((ext_vector_type(4)));

#define DIMF 768
#define NHEAD 12
#define NKV 4096
#define NQ 256
#define NB 16

struct alignas(8) us4 { unsigned short x, y, z, w; };

__device__ __forceinline__ unsigned short f2bf(float x) {
  uint32_t u = __float_as_uint(x);
  u += 0x7fffu + ((u >> 16) & 1u);   // round-to-nearest-even
  return (unsigned short)(u >> 16);
}

__device__ __forceinline__ uint32_t cvtpk(float a, float b) {
  uint32_t r;
  asm("v_cvt_pk_bf16_f32 %0, %1, %2" : "=v"(r) : "v"(a), "v"(b));
  return r;
}

// ---------------- convert f32 -> bf16 (x only) -----------------------------
__global__ void cvt_kernel(const float* __restrict__ in, unsigned short* __restrict__ out, int n) {
  int stride = gridDim.x * blockDim.x * 4;
  for (int i = (blockIdx.x * blockDim.x + threadIdx.x) * 4; i < n; i += stride) {
    float4 v = *(const float4*)(in + i);
    us4 o{f2bf(v.x), f2bf(v.y), f2bf(v.z), f2bf(v.w)};
    *(us4*)(out + i) = o;
  }
}

// ---------------- weight transpose + cvt: Wt[n][k] = W[k][n] ---------------
__global__ void twt_kernel(const float* __restrict__ W0, const float* __restrict__ W1,
                           const float* __restrict__ W2, const float* __restrict__ W3,
                           unsigned short* __restrict__ O0, unsigned short* __restrict__ O1,
                           unsigned short* __restrict__ O2, unsigned short* __restrict__ O3) {
  const float* W; unsigned short* O;
  switch (blockIdx.z) {
    case 0: W = W0; O = O0; break;
    case 1: W = W1; O = O1; break;
    case 2: W = W2; O = O2; break;
    default: W = W3; O = O3; break;
  }
  __shared__ float t[32][33];
  int x0 = blockIdx.x * 32, y0 = blockIdx.y * 32;
  int tx = threadIdx.x, ty = threadIdx.y;
#pragma unroll
  for (int j = 0; j < 4; ++j)
    t[ty + 8 * j][tx] = W[(size_t)(y0 + ty + 8 * j) * DIMF + x0 + tx];
  __syncthreads();
#pragma unroll
  for (int j = 0; j < 4; ++j)
    O[(size_t)(x0 + ty + 8 * j) * DIMF + y0 + tx] = f2bf(t[tx][ty + 8 * j]);
}

// ---------------- GEMM (R5/R8-proven reg-staged): C(128x128) = A * Bt^T -----
// MODE 0: K-proj (+rope_k), A = ctx f32 (in-stage cvt)  [1D grid, XCD swz]
// MODE 1: V-proj,           A = ctx f32 (in-stage cvt)  [1D grid, XCD swz]
// MODE 2: Q-proj (+rope_q, *0.125), A = xb bf16            [2D grid]
// MODE 3: O-proj,                   A = ob bf16 -> f32 out [2D grid]
template <int MODE>
__launch_bounds__(256, 2)
__global__ void gemm_kernel(const void* __restrict__ Ain,
                            const unsigned short* __restrict__ Bt,
                            void* __restrict__ outp,
                            const float* __restrict__ rope) {
  __shared__ unsigned short As[128 * 64];
  __shared__ unsigned short Bs[128 * 64];
  const int t = threadIdx.x;
  const int lane = t & 63, wid = t >> 6;
  const int g = lane >> 4, lc = lane & 15;
  const int wr = wid >> 1, wc = wid & 1;

  int rowBase, colBase;
  if (MODE == 0 || MODE == 1) {
    // 3072%8==0: bijective XCD remap; col (swz%6) fast — A-panel's 6
    // col-blocks adjacent on one XCD (R8: FETCH 254->80MB).
    const int swz = (blockIdx.x & 7) * 384 + (blockIdx.x >> 3);
    rowBase = (swz / 6) * 128;
    colBase = (swz % 6) * 128;
  } else {
    rowBase = blockIdx.x * 128;
    colBase = blockIdx.y * 128;
  }

  const f32x4 z4 = {0.f, 0.f, 0.f, 0.f};
  f32x4 acc[4][4];
#pragma unroll
  for (int m = 0; m < 4; ++m)
#pragma unroll
    for (int n = 0; n < 4; ++n) acc[m][n] = z4;

  const int r0 = t >> 3;   // 0..31 (row within 32-row panel)
  const int c0 = t & 7;    // 16B chunk within 128B k-row

  const float* Af = (const float*)Ain;            // MODE 0/1
  const unsigned short* Ab = (const unsigned short*)Ain;  // MODE 2/3

  f32x4 fa[4][2];   // MODE 0/1: 8 f32 per panel row
  bf16x8 ra[4];     // MODE 2/3
  bf16x8 rbx[4];

#pragma unroll
  for (int pp = 0; pp < 4; ++pp) {
    int row = pp * 32 + r0;
    if constexpr (MODE == 0 || MODE == 1) {
      const float* ap = Af + (size_t)(rowBase + row) * DIMF + c0 * 8;
      fa[pp][0] = *(const f32x4*)ap;
      fa[pp][1] = *(const f32x4*)(ap + 4);
    } else {
      ra[pp] = *(const bf16x8*)(Ab + (size_t)(rowBase + row) * DIMF + c0 * 8);
    }
    rbx[pp] = *(const bf16x8*)(Bt + (size_t)(colBase + row) * DIMF + c0 * 8);
  }

  for (int kb = 0; kb < 12; ++kb) {
    __syncthreads();
#pragma unroll
    for (int pp = 0; pp < 4; ++pp) {
      int row = pp * 32 + r0;
      int ph = ((c0 ^ (row & 7)) << 3);
      if constexpr (MODE == 0 || MODE == 1) {
        u32x4 pw = {cvtpk(fa[pp][0][0], fa[pp][0][1]),
                    cvtpk(fa[pp][0][2], fa[pp][0][3]),
                    cvtpk(fa[pp][1][0], fa[pp][1][1]),
                    cvtpk(fa[pp][1][2], fa[pp][1][3])};
        *(u32x4*)&As[row * 64 + ph] = pw;
      } else {
        *(bf16x8*)&As[row * 64 + ph] = ra[pp];
      }
      *(bf16x8*)&Bs[row * 64 + ph] = rbx[pp];
    }
    __syncthreads();
    if (kb + 1 < 12) {
      int kn = (kb + 1) * 64;
#pragma unroll
      for (int pp = 0; pp < 4; ++pp) {
        int row = pp * 32 + r0;
        if constexpr (MODE == 0 || MODE == 1) {
          const float* ap = Af + (size_t)(rowBase + row) * DIMF + kn + c0 * 8;
          fa[pp][0] = *(const f32x4*)ap;
          fa[pp][1] = *(const f32x4*)(ap + 4);
        } else {
          ra[pp] = *(const bf16x8*)(Ab + (size_t)(rowBase + row) * DIMF + kn + c0 * 8);
        }
        rbx[pp] = *(const bf16x8*)(Bt + (size_t)(colBase + row) * DIMF + kn + c0 * 8);
      }
    }
#pragma unroll
    for (int kk = 0; kk < 2; ++kk) {
      bf16x8 af[4], bfr[4];
#pragma unroll
      for (int m = 0; m < 4; ++m) {
        int row = wr * 64 + m * 16 + lc;
        int ch = kk * 4 + g;
        af[m] = *(const bf16x8*)&As[row * 64 + (((ch ^ (row & 7))) << 3)];
      }
#pragma unroll
      for (int n = 0; n < 4; ++n) {
        int row = wc * 64 + n * 16 + lc;
        int ch = kk * 4 + g;
        bfr[n] = *(const bf16x8*)&Bs[row * 64 + (((ch ^ (row & 7))) << 3)];
      }
#pragma unroll
      for (int m = 0; m < 4; ++m)
#pragma unroll
        for (int n = 0; n < 4; ++n)
          acc[m][n] = __builtin_amdgcn_mfma_f32_16x16x32_bf16(af[m], bfr[n], acc[m][n], 0, 0, 0);
    }
  }

  if (MODE == 0 || MODE == 2) {
    unsigned short* Ko = (unsigned short*)outp;
#pragma unroll
    for (int m = 0; m < 4; ++m)
#pragma unroll
      for (int n = 0; n < 4; ++n)
#pragma unroll
        for (int r = 0; r < 4; ++r) {
          int p = rowBase + wr * 64 + m * 16 + g * 4 + r;
          int f = colBase + wc * 64 + n * 16 + lc;
          int d = f & 63, h = f >> 6;
          float v = acc[m][n][r];
          float vo = __shfl_xor(v, 1);
          if (MODE == 0) {
            int b = p >> 12, nkv = p & 4095;
            float sn = rope[nkv * 128 + d], cs = rope[nkv * 128 + 64 + d];
            float o = (d & 1) ? fmaf(vo, sn, v * cs) : fmaf(-vo, sn, v * cs);
            Ko[((size_t)(b * NHEAD + h) * NKV + nkv) * 64 + d] = f2bf(o);
          } else {
            int b = p >> 8, nq = p & 255;
            float sn = rope[nq * 128 + d], cs = rope[nq * 128 + 64 + d];
            float o = (d & 1) ? fmaf(vo, sn, v * cs) : fmaf(-vo, sn, v * cs);
            Ko[((size_t)(b * NHEAD + h) * NQ + nq) * 64 + d] = f2bf(o * 0.125f);
          }
        }
  } else if (MODE == 1) {
    unsigned short* Vt = (unsigned short*)outp;
#pragma unroll
    for (int m = 0; m < 4; ++m)
#pragma unroll
      for (int n = 0; n < 4; ++n) {
        int p0 = rowBase + wr * 64 + m * 16 + g * 4;
        int b = p0 >> 12, nkv0 = p0 & 4095;
        int f = colBase + wc * 64 + n * 16 + lc;
        int d = f & 63, h = f >> 6;
        us4 wv{f2bf(acc[m][n][0]), f2bf(acc[m][n][1]), f2bf(acc[m][n][2]), f2bf(acc[m][n][3])};
        *(us4*)&Vt[((size_t)(b * NHEAD + h) * 64 + d) * NKV + nkv0] = wv;
      }
  } else {
    float* Co = (float*)outp;
#pragma unroll
    for (int m = 0; m < 4; ++m)
#pragma unroll
      for (int n = 0; n < 4; ++n)
#pragma unroll
        for (int r = 0; r < 4; ++r) {
          int p = rowBase + wr * 64 + m * 16 + g * 4 + r;
          int f = colBase + wc * 64 + n * 16 + lc;
          Co[(size_t)p * DIMF + f] = acc[m][n][r];
        }
  }
}

// ---------------- flash attention (R5-proven, verbatim) --------------------
__launch_bounds__(256, 2)
__global__ void attn_kernel(const unsigned short* __restrict__ Qb,
                            const unsigned short* __restrict__ Kb,
                            const unsigned short* __restrict__ Vtb,
                            unsigned short* __restrict__ Ob) {
  __shared__ unsigned short Ks[128 * 64];    // [kv][d]  16KB, chunk ^= (kv&7)
  __shared__ unsigned short Vts[64 * 128];   // [d][kv'] 16KB, chunk ^= (d&15)
  const int logical = (blockIdx.x & 7) * 96 + (blockIdx.x >> 3);  // 768%8==0
  const int qt = logical & 3, bh = logical >> 2;
  const int b = bh / NHEAD, h = bh % NHEAD;
  const int t = threadIdx.x;
  const int lane = t & 63, w = t >> 6;
  const int g = lane >> 4, lc = lane & 15;
  const int qrow = qt * 64 + w * 16 + lc;

  bf16x8 qf[2];
#pragma unroll
  for (int kk = 0; kk < 2; ++kk)
    qf[kk] = *(const bf16x8*)(Qb + ((size_t)bh * NQ + qrow) * 64 + kk * 32 + g * 8);

  const f32x4 z4 = {0.f, 0.f, 0.f, 0.f};
  f32x4 oacc[4];
#pragma unroll
  for (int df = 0; df < 4; ++df) oacc[df] = z4;
  float mrun = -1e30f, lrun = 0.f;

  const int r0 = t >> 3, c0 = t & 7;
  const int d0 = t >> 4, cv = t & 15;
  const int pbase = 32 * (cv >> 2) + 16 * (cv & 1) + 4 * ((cv >> 1) & 1);
  const int ch0 = pbase >> 3, of0 = pbase & 7;
  const int ch1 = (pbase + 8) >> 3;

  u16x8 rk[4], rv[4];
#define LOAD_TILE(KT)                                                                        \
  do {                                                                                       \
    const int kvb = (KT) * 128;                                                              \
    _Pragma("unroll")                                                                        \
    for (int pp = 0; pp < 4; ++pp)                                                           \
      rk[pp] = *(const u16x8*)(Kb + ((size_t)bh * NKV + kvb + pp * 32 + r0) * 64 + c0 * 8);  \
    _Pragma("unroll")                                                                        \
    for (int pp = 0; pp < 4; ++pp)                                                           \
      rv[pp] = *(const u16x8*)(Vtb + ((size_t)bh * 64 + pp * 16 + d0) * NKV + kvb + cv * 8); \
  } while (0)

  LOAD_TILE(0);

  for (int kt = 0; kt < 32; ++kt) {
    __syncthreads();
#pragma unroll
    for (int pp = 0; pp < 4; ++pp) {
      int row = pp * 32 + r0;
      *(u16x8*)&Ks[row * 64 + ((c0 ^ (row & 7)) << 3)] = rk[pp];
    }
#pragma unroll
    for (int pp = 0; pp < 4; ++pp) {
      int d = pp * 16 + d0;
      u16x4 lo = __builtin_shufflevector(rv[pp], rv[pp], 0, 1, 2, 3);
      u16x4 hi = __builtin_shufflevector(rv[pp], rv[pp], 4, 5, 6, 7);
      *(u16x4*)&Vts[d * 128 + ((ch0 ^ (d & 15)) << 3) + of0] = lo;
      *(u16x4*)&Vts[d * 128 + ((ch1 ^ (d & 15)) << 3) + of0] = hi;
    }
    if (kt + 1 < 32) LOAD_TILE(kt + 1);
    __syncthreads();

    f32x4 s[8];
#pragma unroll
    for (int c = 0; c < 8; ++c) s[c] = z4;
#pragma unroll
    for (int kk = 0; kk < 2; ++kk)
#pragma unroll
      for (int c = 0; c < 8; ++c) {
        int row = c * 16 + lc;
        bf16x8 kf = *(const bf16x8*)&Ks[row * 64 + (((kk * 4 + g) ^ (row & 7)) << 3)];
        s[c] = __builtin_amdgcn_mfma_f32_16x16x32_bf16(kf, qf[kk], s[c], 0, 0, 0);
      }

    float mx = s[0][0];
#pragma unroll
    for (int c = 0; c < 8; ++c)
#pragma unroll
      for (int r = 0; r < 4; ++r) mx = fmaxf(mx, s[c][r]);
    mx = fmaxf(mx, __shfl_xor(mx, 16));
    mx = fmaxf(mx, __shfl_xor(mx, 32));
    float nm = fmaxf(mrun, mx);
    float al = __expf(mrun - nm);
    mrun = nm;
    float ls = 0.f;
#pragma unroll
    for (int c = 0; c < 8; ++c)
#pragma unroll
      for (int r = 0; r < 4; ++r) {
        float p = __expf(s[c][r] - nm);
        s[c][r] = p;
        ls += p;
      }
    ls += __shfl_xor(ls, 16);
    ls += __shfl_xor(ls, 32);
    lrun = lrun * al + ls;
#pragma unroll
    for (int df = 0; df < 4; ++df)
#pragma unroll
      for (int r = 0; r < 4; ++r) oacc[df][r] *= al;

    uint32_t pk[8][2];
#pragma unroll
    for (int c = 0; c < 8; ++c)
#pragma unroll
      for (int w2 = 0; w2 < 2; ++w2)
        pk[c][w2] = cvtpk(s[c][2 * w2], s[c][2 * w2 + 1]);

#pragma unroll
    for (int kb = 0; kb < 4; ++kb) {
      u32x4 pw = {pk[2 * kb][0], pk[2 * kb][1], pk[2 * kb + 1][0], pk[2 * kb + 1][1]};
      bf16x8 pa = __builtin_bit_cast(bf16x8, pw);
#pragma unroll
      for (int df = 0; df < 4; ++df) {
        int row = df * 16 + lc;
        bf16x8 vf = *(const bf16x8*)&Vts[row * 128 + (((kb * 4 + g) ^ (row & 15)) << 3)];
        oacc[df] = __builtin_amdgcn_mfma_f32_16x16x32_bf16(vf, pa, oacc[df], 0, 0, 0);
      }
    }
  }
#undef LOAD_TILE

  float inv = 1.0f / lrun;
#pragma unroll
  for (int df = 0; df < 4; ++df) {
    us4 wv{f2bf(oacc[df][0] * inv), f2bf(oacc[df][1] * inv),
           f2bf(oacc[df][2] * inv), f2bf(oacc[df][3] * inv)};
    *(us4*)&Ob[((size_t)b * NQ + qrow) * DIMF + h * 64 + df * 16 + g * 4] = wv;
  }
}

// ---------------- launch ----------------------------------------------------
extern "C" void kernel_launch(void* const* d_in, const int* in_sizes, int n_in,
                              void* d_out, int out_size, void* d_ws, size_t ws_size,
                              hipStream_t stream) {
  const float* x      = (const float*)d_in[0];
  const float* ctx    = (const float*)d_in[1];
  const float* rope_q = (const float*)d_in[2];
  const float* rope_k = (const float*)d_in[3];
  const float* Wq     = (const float*)d_in[4];
  const float* Wk     = (const float*)d_in[5];
  const float* Wv     = (const float*)d_in[6];
  const float* Wo     = (const float*)d_in[7];

  char* ws = (char*)d_ws;
  const size_t SZ_CTXB = (size_t)NB * NKV * DIMF * 2;
  const size_t SZ_XB   = (size_t)NB * NQ * DIMF * 2;
  const size_t SZ_WT   = (size_t)DIMF * DIMF * 2;
  unsigned short* ob   = (unsigned short*)(ws);                       // ctxb slot (now free)
  unsigned short* xb   = (unsigned short*)(ws + SZ_CTXB);
  unsigned short* wkt  = (unsigned short*)(ws + SZ_CTXB + SZ_XB);
  unsigned short* wvt  = (unsigned short*)(ws + SZ_CTXB + SZ_XB + SZ_WT);
  unsigned short* wqt  = (unsigned short*)(ws + SZ_CTXB + SZ_XB + 2 * SZ_WT);
  unsigned short* wot  = (unsigned short*)(ws + SZ_CTXB + SZ_XB + 3 * SZ_WT);
  unsigned short* kb   = (unsigned short*)(ws + SZ_CTXB + SZ_XB + 4 * SZ_WT);
  unsigned short* vtb  = (unsigned short*)(ws + SZ_CTXB + SZ_XB + 4 * SZ_WT + SZ_CTXB);
  unsigned short* qb   = (unsigned short*)(ws + SZ_CTXB + SZ_XB + 4 * SZ_WT + 2 * SZ_CTXB);

  cvt_kernel<<<dim3(1024), dim3(256), 0, stream>>>(x, xb, NB * NQ * DIMF);
  twt_kernel<<<dim3(24, 24, 4), dim3(32, 8), 0, stream>>>(Wk, Wv, Wq, Wo, wkt, wvt, wqt, wot);

  gemm_kernel<0><<<dim3(3072), dim3(256), 0, stream>>>(ctx, wkt, kb, rope_k);
  gemm_kernel<1><<<dim3(3072), dim3(256), 0, stream>>>(ctx, wvt, vtb, nullptr);
  gemm_kernel<2><<<dim3(32, 6), dim3(256), 0, stream>>>(xb, wqt, qb, rope_q);

  attn_kernel<<<dim3(768), dim3(256), 0, stream>>>(qb, kb, vtb, ob);

  gemm_kernel<3><<<dim3(32, 6), dim3(256), 0, stream>>>(ob, wot, d_out, nullptr);
}